// Round 4
// baseline (417.239 us; speedup 1.0000x reference)
//
#include <hip/hip_runtime.h>
#include <cstdint>
#include <cstddef>

typedef __bf16 bf16x8 __attribute__((ext_vector_type(8)));
typedef float f32x4 __attribute__((ext_vector_type(4)));
using u16 = unsigned short;
using u32 = unsigned int;

// ---------- helpers ----------
__device__ __forceinline__ u16 f2b(float f) {
  u32 u = __float_as_uint(f);
  u32 r = u + 0x7FFFu + ((u >> 16) & 1u);
  return (u16)(r >> 16);
}
__device__ __forceinline__ float b2f(u16 h) { return __uint_as_float((u32)h << 16); }

__device__ __forceinline__ void gload16(const void* g, void* l) {
  __builtin_amdgcn_global_load_lds((const __attribute__((address_space(1))) void*)g,
                                   (__attribute__((address_space(3))) void*)l, 16, 0, 0);
}

__device__ __forceinline__ u32 mapf(float f) {
  u32 u = __float_as_uint(f);
  return (u & 0x80000000u) ? ~u : (u | 0x80000000u);
}
__device__ __forceinline__ float unmapf(u32 k) {
  u32 u = (k & 0x80000000u) ? (k ^ 0x80000000u) : ~k;
  return __uint_as_float(u);
}
__device__ __forceinline__ u32 cvtpk(float lo, float hi) {
  u32 r;
  asm("v_cvt_pk_bf16_f32 %0, %1, %2" : "=v"(r) : "v"(lo), "v"(hi));
  return r;
}

#define MFMA __builtin_amdgcn_mfma_f32_16x16x32_bf16

// ---------- positional encoding (f32 + split bf16) ----------
__global__ void pe_kernel(float* __restrict__ pe, u16* __restrict__ peh, u16* __restrict__ pel) {
  int i = blockIdx.x * 256 + threadIdx.x;
  if (i >= 512 * 512) return;
  int t = i >> 9, d = i & 511;
  double ang = (double)t * exp((double)d * (-2.0 / 512.0) * log(10000.0));
  double v = (d & 1) ? cos(ang) : sin(ang);
  float p = (float)(v * 22.627416997969522);
  pe[i] = p;
  u16 h = f2b(p);
  peh[i] = h;
  pel[i] = f2b(p - b2f(h));
}

// ---------- weight conversion / transposition ----------
__global__ void wconv_kernel(const float* __restrict__ WQ, const float* __restrict__ WK,
                             const float* __restrict__ WV, const float* __restrict__ f1,
                             const float* __restrict__ f2,
                             u16* __restrict__ WQth, u16* __restrict__ WQtl,
                             u16* __restrict__ WKth, u16* __restrict__ WKtl,
                             u16* __restrict__ WKb, u16* __restrict__ WVt,
                             u16* __restrict__ f1t, u16* __restrict__ f2t,
                             u16* __restrict__ zb) {
  int i = blockIdx.x * 256 + threadIdx.x;
  if (i < 262144) {
    int n = i >> 9, k = i & 511;
    float wq = WQ[k * 512 + n];
    u16 h = f2b(wq);
    WQth[i] = h;
    WQtl[i] = f2b(wq - b2f(h));
    float wk = WK[k * 512 + n];
    h = f2b(wk);
    WKth[i] = h;
    WKtl[i] = f2b(wk - b2f(h));
    WKb[i] = f2b(WK[i]);
    WVt[i] = f2b(WV[k * 512 + n]);
    zb[i] = 0;
  } else if (i < 262144 + 1048576) {
    int i2 = i - 262144;
    int n = i2 >> 9, k = i2 & 511;
    f1t[i2] = f2b(f1[k * 2048 + n]);
  } else if (i < 262144 + 2097152) {
    int i3 = i - 262144 - 1048576;
    int n = i3 >> 11, k = i3 & 2047;
    f2t[i3] = f2b(f2[k * 512 + n]);
  }
}

// ---------- q1 (split bf16) + m_ws zero-init ----------
__global__ void prep_kernel(const float* __restrict__ q, const float* __restrict__ pe,
                            u16* __restrict__ q1h, u16* __restrict__ q1l,
                            u32* __restrict__ m0) {
  int i = blockIdx.x * 256 + threadIdx.x;
  if (i < 131072) m0[i] = 0u;  // mapf(-inf) == 0
  if (i >= 32 * 512 * 512) return;
  int td = i & (262144 - 1);
  float q1 = q[i] + pe[td];
  u16 h = f2b(q1);
  q1h[i] = h;
  q1l[i] = f2b(q1 - b2f(h));
}

// ---------- generic GEMM: C[M,N] = A[M,K] * B^T ----------
#define GM_BF16 0
#define GM_RELU 2
#define GM_ADDF32 3
#define GM_BF16PE 4

template <int MODE>
__global__ __launch_bounds__(256, 3) void gemm_bt(const u16* __restrict__ A,
                                                  const u16* __restrict__ B, int M, int N, int K,
                                                  u16* __restrict__ outb, float* __restrict__ outf,
                                                  const float* __restrict__ res,
                                                  const float* __restrict__ peadd) {
  __shared__ u16 As[128 * 32];
  __shared__ u16 Bs[128 * 32];
  const int tid = threadIdx.x, lane = tid & 63, w = tid >> 6;
  const int wm = w >> 1, wn = w & 1;
  const long aBase = (long)blockIdx.x * 128;
  const long bBase = (long)blockIdx.y * 128;
  f32x4 acc[4][4] = {};
  const int nk = K >> 5;
  for (int kt = 0; kt < nk; ++kt) {
#pragma unroll
    for (int i = 0; i < 2; ++i) {
      const int c = w * 2 + i;
      const int off = c * 1024 + lane * 16;
      const int r = off >> 6, cb = off & 63;
      gload16((const char*)A + ((aBase + r) * (long)K + (long)kt * 32) * 2 + cb,
              (char*)As + c * 1024);
      gload16((const char*)B + ((bBase + r) * (long)K + (long)kt * 32) * 2 + cb,
              (char*)Bs + c * 1024);
    }
    __syncthreads();
    bf16x8 af[4], bfr[4];
#pragma unroll
    for (int x = 0; x < 4; ++x) {
      af[x] = *(const bf16x8*)&As[(wm * 64 + x * 16 + (lane & 15)) * 32 + (lane >> 4) * 8];
      bfr[x] = *(const bf16x8*)&Bs[(wn * 64 + x * 16 + (lane & 15)) * 32 + (lane >> 4) * 8];
    }
#pragma unroll
    for (int mf = 0; mf < 4; ++mf)
#pragma unroll
      for (int nf = 0; nf < 4; ++nf)
        acc[mf][nf] = MFMA(af[mf], bfr[nf], acc[mf][nf], 0, 0, 0);
    __syncthreads();
  }
#pragma unroll
  for (int mf = 0; mf < 4; ++mf)
#pragma unroll
    for (int nf = 0; nf < 4; ++nf) {
      const long row0 = aBase + wm * 64 + mf * 16 + (lane >> 4) * 4;
      const long col = bBase + wn * 64 + nf * 16 + (lane & 15);
#pragma unroll
      for (int j = 0; j < 4; ++j) {
        float v = acc[mf][nf][j];
        const long row = row0 + j;
        if constexpr (MODE == GM_BF16)
          outb[row * N + col] = f2b(v);
        else if constexpr (MODE == GM_RELU)
          outb[row * N + col] = f2b(v > 0.f ? v : 0.f);
        else if constexpr (MODE == GM_BF16PE)
          outb[row * N + col] = f2b(v + peadd[row * 512 + (col & 511)]);
        else
          outf[row * N + col] = res[row * N + col] + v;
      }
    }
}

// ---------- split-precision GEMM: OUT 0 = split store, 1 = +PE then split, 2 = f32 out ----------
template <int OUT>
__global__ __launch_bounds__(256, 2) void gemm_split(const u16* __restrict__ Ah,
                                                     const u16* __restrict__ Al,
                                                     const u16* __restrict__ Bh,
                                                     const u16* __restrict__ Bl, int M, int N,
                                                     int K, u16* __restrict__ Oh,
                                                     u16* __restrict__ Ol,
                                                     float* __restrict__ Of,
                                                     const float* __restrict__ peadd) {
  __shared__ u16 Ash[4096], Asl[4096], Bsh[4096], Bsl[4096];
  const int tid = threadIdx.x, lane = tid & 63, w = tid >> 6;
  const int wm = w >> 1, wn = w & 1;
  const long aBase = (long)blockIdx.x * 128;
  const long bBase = (long)blockIdx.y * 128;
  f32x4 acc[4][4] = {};
  const int nk = K >> 5;
  for (int kt = 0; kt < nk; ++kt) {
#pragma unroll
    for (int i = 0; i < 2; ++i) {
      const int c = w * 2 + i;
      const int off = c * 1024 + lane * 16;
      const int r = off >> 6, cb = off & 63;
      long ga = ((aBase + r) * (long)K + (long)kt * 32) * 2 + cb;
      long gb = ((bBase + r) * (long)K + (long)kt * 32) * 2 + cb;
      gload16((const char*)Ah + ga, (char*)Ash + c * 1024);
      gload16((const char*)Al + ga, (char*)Asl + c * 1024);
      gload16((const char*)Bh + gb, (char*)Bsh + c * 1024);
      gload16((const char*)Bl + gb, (char*)Bsl + c * 1024);
    }
    __syncthreads();
    bf16x8 ah[4], al[4], bh[4], bl[4];
#pragma unroll
    for (int x = 0; x < 4; ++x) {
      int ao = (wm * 64 + x * 16 + (lane & 15)) * 32 + (lane >> 4) * 8;
      int bo = (wn * 64 + x * 16 + (lane & 15)) * 32 + (lane >> 4) * 8;
      ah[x] = *(const bf16x8*)&Ash[ao];
      al[x] = *(const bf16x8*)&Asl[ao];
      bh[x] = *(const bf16x8*)&Bsh[bo];
      bl[x] = *(const bf16x8*)&Bsl[bo];
    }
#pragma unroll
    for (int mf = 0; mf < 4; ++mf)
#pragma unroll
      for (int nf = 0; nf < 4; ++nf) {
        acc[mf][nf] = MFMA(ah[mf], bh[nf], acc[mf][nf], 0, 0, 0);
        acc[mf][nf] = MFMA(ah[mf], bl[nf], acc[mf][nf], 0, 0, 0);
        acc[mf][nf] = MFMA(al[mf], bh[nf], acc[mf][nf], 0, 0, 0);
      }
    __syncthreads();
  }
#pragma unroll
  for (int mf = 0; mf < 4; ++mf)
#pragma unroll
    for (int nf = 0; nf < 4; ++nf) {
      const long row0 = aBase + wm * 64 + mf * 16 + (lane >> 4) * 4;
      const long col = bBase + wn * 64 + nf * 16 + (lane & 15);
#pragma unroll
      for (int j = 0; j < 4; ++j) {
        float v = acc[mf][nf][j];
        const long row = row0 + j;
        if constexpr (OUT == 1) v += peadd[(row & 511) * 512 + col];
        if constexpr (OUT == 2) {
          Of[row * N + col] = v;
        } else {
          u16 h = f2b(v);
          Oh[row * N + col] = h;
          Ol[row * N + col] = f2b(v - b2f(h));
        }
      }
    }
}

// ---------- attention pass 1: column max over q, per (h,b,k) ----------
__global__ __launch_bounds__(256, 4) void attn_colmax(const u16* __restrict__ Qh,
                                                      const u16* __restrict__ Ql,
                                                      const u16* __restrict__ Kh,
                                                      const u16* __restrict__ Kl,
                                                      u32* __restrict__ mg) {
  __shared__ u16 Qsh[4096], Qsl[4096];  // [64 rows][64 u16], XOR-swizzled
  __shared__ u16 Ksh[4096], Ksl[4096];
  __shared__ u32 mloc[512];
  const int tid = threadIdx.x, lane = tid & 63, w = tid >> 6;
  const int ql = lane & 15, g = lane >> 4;
  const int hb = blockIdx.x, b = hb >> 3, h = hb & 7, qc = blockIdx.y;
  mloc[tid] = 0u;
  mloc[tid + 256] = 0u;
  const int srccb = 16 * ((lane & 7) ^ ((lane >> 3) & 7));
#pragma unroll
  for (int i = 0; i < 2; ++i) {
    const int c = w * 2 + i;
    const int r = c * 8 + (lane >> 3);
    long gb = ((long)(b * 512 + qc * 64 + r) * 512 + h * 64) * 2 + srccb;
    gload16((const char*)Qh + gb, (char*)Qsh + c * 1024);
    gload16((const char*)Ql + gb, (char*)Qsl + c * 1024);
  }
  __syncthreads();
  const int qrow = w * 16 + ql;
  const int sw0 = ((g * 16) ^ ((ql & 7) * 16)) >> 1;
  const int sw1 = ((64 + g * 16) ^ ((ql & 7) * 16)) >> 1;
  bf16x8 qh0 = *(const bf16x8*)&Qsh[qrow * 64 + sw0];
  bf16x8 ql0 = *(const bf16x8*)&Qsl[qrow * 64 + sw0];
  bf16x8 qh1 = *(const bf16x8*)&Qsh[qrow * 64 + sw1];
  bf16x8 ql1 = *(const bf16x8*)&Qsl[qrow * 64 + sw1];
  for (int kc = 0; kc < 8; ++kc) {
#pragma unroll
    for (int i = 0; i < 2; ++i) {
      const int c = w * 2 + i;
      const int r = c * 8 + (lane >> 3);
      long gb = ((long)(b * 512 + kc * 64 + r) * 512 + h * 64) * 2 + srccb;
      gload16((const char*)Kh + gb, (char*)Ksh + c * 1024);
      gload16((const char*)Kl + gb, (char*)Ksl + c * 1024);
    }
    __syncthreads();
#pragma unroll
    for (int kt = 0; kt < 4; ++kt) {
      const int krow = kt * 16 + ql;
      bf16x8 kh0 = *(const bf16x8*)&Ksh[krow * 64 + sw0];
      bf16x8 kl0 = *(const bf16x8*)&Ksl[krow * 64 + sw0];
      bf16x8 kh1 = *(const bf16x8*)&Ksh[krow * 64 + sw1];
      bf16x8 kl1 = *(const bf16x8*)&Ksl[krow * 64 + sw1];
      f32x4 acc = {0.f, 0.f, 0.f, 0.f};
      acc = MFMA(qh0, kh0, acc, 0, 0, 0);
      acc = MFMA(qh0, kl0, acc, 0, 0, 0);
      acc = MFMA(ql0, kh0, acc, 0, 0, 0);
      acc = MFMA(qh1, kh1, acc, 0, 0, 0);
      acc = MFMA(qh1, kl1, acc, 0, 0, 0);
      acc = MFMA(ql1, kh1, acc, 0, 0, 0);
      float v = fmaxf(fmaxf(acc[0], acc[1]), fmaxf(acc[2], acc[3]));
      v = fmaxf(v, __shfl_xor(v, 16));
      v = fmaxf(v, __shfl_xor(v, 32));
      if (lane < 16) atomicMax(&mloc[kc * 64 + kt * 16 + ql], mapf(v));
    }
    __syncthreads();
  }
  for (int k = tid; k < 512; k += 256) atomicMax(&mg[(long)hb * 512 + k], mloc[k]);
}

// ---------- attention pass 2: S^T + in-register softmax/transpose + PV(V from global) ----------
__global__ __launch_bounds__(256, 2) void attn_main(
    const u16* __restrict__ Qh, const u16* __restrict__ Ql, const u16* __restrict__ Kh,
    const u16* __restrict__ Kl, const u16* __restrict__ Vt, const u32* __restrict__ mg,
    const int* __restrict__ qmask, const float* __restrict__ queries,
    const float* __restrict__ pe, float* __restrict__ resf, u16* __restrict__ resb) {
  __shared__ u16 Qsh[4096], Qsl[4096];  // [64][64] u16, XOR-swizzled
  __shared__ u16 Ksh[4096], Ksl[4096];
  __shared__ float mks[512];
  const int tid = threadIdx.x, lane = tid & 63, w = tid >> 6;
  const int ql = lane & 15, g = lane >> 4;
  const int hb = blockIdx.x, b = hb >> 3, h = hb & 7, qc = blockIdx.y;
  const int qm = qmask[b];
  for (int k = tid; k < 512; k += 256) mks[k] = 0.125f * unmapf(mg[(long)hb * 512 + k]);
  const int srccb = 16 * ((lane & 7) ^ ((lane >> 3) & 7));
#pragma unroll
  for (int i = 0; i < 2; ++i) {
    const int c = w * 2 + i;
    const int r = c * 8 + (lane >> 3);
    long gb = ((long)(b * 512 + qc * 64 + r) * 512 + h * 64) * 2 + srccb;
    gload16((const char*)Qh + gb, (char*)Qsh + c * 1024);
    gload16((const char*)Ql + gb, (char*)Qsl + c * 1024);
  }
  __syncthreads();
  const int qrow = w * 16 + ql;
  const int sw0 = ((g * 16) ^ ((ql & 7) * 16)) >> 1;
  const int sw1 = ((64 + g * 16) ^ ((ql & 7) * 16)) >> 1;
  bf16x8 qh0 = *(const bf16x8*)&Qsh[qrow * 64 + sw0];
  bf16x8 qh1 = *(const bf16x8*)&Qsh[qrow * 64 + sw1];
  // S^T accumulators (MUST stay register-resident: all indices compile-time)
  f32x4 s[32] = {};
#pragma unroll
  for (int kc = 0; kc < 8; ++kc) {
#pragma unroll
    for (int i = 0; i < 2; ++i) {
      const int c = w * 2 + i;
      const int r = c * 8 + (lane >> 3);
      long gb = ((long)(b * 512 + kc * 64 + r) * 512 + h * 64) * 2 + srccb;
      gload16((const char*)Kh + gb, (char*)Ksh + c * 1024);
      gload16((const char*)Kl + gb, (char*)Ksl + c * 1024);
    }
    __syncthreads();
    bf16x8 qlo0 = *(const bf16x8*)&Qsl[qrow * 64 + sw0];
    bf16x8 qlo1 = *(const bf16x8*)&Qsl[qrow * 64 + sw1];
#pragma unroll
    for (int kt = 0; kt < 4; ++kt) {
      const int krow = kt * 16 + ql;
      bf16x8 kh0 = *(const bf16x8*)&Ksh[krow * 64 + sw0];
      bf16x8 kl0 = *(const bf16x8*)&Ksl[krow * 64 + sw0];
      bf16x8 kh1 = *(const bf16x8*)&Ksh[krow * 64 + sw1];
      bf16x8 kl1 = *(const bf16x8*)&Ksl[krow * 64 + sw1];
      const int fi = kc * 4 + kt;
      s[fi] = MFMA(kh0, qh0, s[fi], 0, 0, 0);
      s[fi] = MFMA(kh0, qlo0, s[fi], 0, 0, 0);
      s[fi] = MFMA(kl0, qh0, s[fi], 0, 0, 0);
      s[fi] = MFMA(kh1, qh1, s[fi], 0, 0, 0);
      s[fi] = MFMA(kh1, qlo1, s[fi], 0, 0, 0);
      s[fi] = MFMA(kl1, qh1, s[fi], 0, 0, 0);
    }
    __syncthreads();
  }
  // softmax: z = s/8 - m[k]; rowmax (lane-local + 2 shfl); exp; sum; mask
  float pmax = -3.4e38f;
#pragma unroll
  for (int fi = 0; fi < 32; ++fi) {
    f32x4 mrow = *(const f32x4*)&mks[fi * 16 + g * 4];
#pragma unroll
    for (int j = 0; j < 4; ++j) {
      float z = s[fi][j] * 0.125f - mrow[j];
      s[fi][j] = z;
      pmax = fmaxf(pmax, z);
    }
  }
  pmax = fmaxf(pmax, __shfl_xor(pmax, 16));
  pmax = fmaxf(pmax, __shfl_xor(pmax, 32));
  float rsum = 0.f;
#pragma unroll
  for (int fi = 0; fi < 32; ++fi)
#pragma unroll
    for (int j = 0; j < 4; ++j) {
      float p = __expf(s[fi][j] - pmax);
      s[fi][j] = p;
      rsum += p;
    }
  rsum += __shfl_xor(rsum, 16);
  rsum += __shfl_xor(rsum, 32);
  const int qg = qc * 64 + w * 16 + ql;
  const float sc = (qg < qm) ? (1.0f / rsum) : 0.0f;
  // pack P to bf16 pairs
  u32 pk0[32], pk1[32];
#pragma unroll
  for (int fi = 0; fi < 32; ++fi) {
    pk0[fi] = cvtpk(s[fi][0] * sc, s[fi][1] * sc);
    pk1[fi] = cvtpk(s[fi][2] * sc, s[fi][3] * sc);
  }
  // PV: O^T[d][q] = sum_k V^T[d][k] P[q][k]; A = V^T frag from global, B = P (shfl)
  f32x4 o[4] = {};
  const int src0 = (g & 1) * 32 + ql;
  const int src1 = src0 + 16;
  const bool lowh = g < 2;
  const u16* vb = Vt + (long)(h * 64) * 16384 + b * 512;
#pragma unroll
  for (int ks = 0; ks < 16; ++ks) {
    const int fA = 2 * ks, fB = 2 * ks + 1;
    u32 a00 = __shfl(pk0[fA], src0), b00 = __shfl(pk0[fB], src0);
    u32 a10 = __shfl(pk1[fA], src0), b10 = __shfl(pk1[fB], src0);
    u32 a01 = __shfl(pk0[fA], src1), b01 = __shfl(pk0[fB], src1);
    u32 a11 = __shfl(pk1[fA], src1), b11 = __shfl(pk1[fB], src1);
    union {
      u32 u[4];
      bf16x8 v;
    } pf;
    pf.u[0] = lowh ? a00 : b00;
    pf.u[1] = lowh ? a10 : b10;
    pf.u[2] = lowh ? a01 : b01;
    pf.u[3] = lowh ? a11 : b11;
#pragma unroll
    for (int nf = 0; nf < 4; ++nf) {
      bf16x8 vf = *(const bf16x8*)&vb[(long)(nf * 16 + ql) * 16384 + ks * 32 + g * 8];
      o[nf] = MFMA(vf, pf.v, o[nf], 0, 0, 0);
    }
  }
  // epilogue: O[q][d] + queries + pe -> resf (f32) and resb (bf16)
#pragma unroll
  for (int nf = 0; nf < 4; ++nf) {
    const int col = h * 64 + nf * 16 + g * 4;
    const long idx = (long)(b * 512 + qg) * 512 + col;
    float4 qv = *(const float4*)&queries[idx];
    float4 pv = *(const float4*)&pe[qg * 512 + col];
    float v0 = o[nf][0] + qv.x + pv.x;
    float v1 = o[nf][1] + qv.y + pv.y;
    float v2 = o[nf][2] + qv.z + pv.z;
    float v3 = o[nf][3] + qv.w + pv.w;
    *(float4*)&resf[idx] = make_float4(v0, v1, v2, v3);
    ushort4 rb = {f2b(v0), f2b(v1), f2b(v2), f2b(v3)};
    *(ushort4*)&resb[idx] = rb;
  }
}

// ---------- launch ----------
extern "C" void kernel_launch(void* const* d_in, const int* in_sizes, int n_in, void* d_out,
                              int out_size, void* d_ws, size_t ws_size, hipStream_t stream) {
  (void)in_sizes;
  (void)n_in;
  (void)out_size;
  (void)ws_size;
  const float* queries = (const float*)d_in[0];
  const int* qmask = (const int*)d_in[2];
  const float* WQ = (const float*)d_in[4];
  const float* WK = (const float*)d_in[5];
  const float* WV = (const float*)d_in[6];
  const float* f1 = (const float*)d_in[7];
  const float* f2 = (const float*)d_in[8];
  float* out = (float*)d_out;
  char* ws = (char*)d_ws;
  const size_t A = 16777216;
  u16* q1h = (u16*)(ws + 0 * A);
  u16* q1l = (u16*)(ws + 1 * A);
  u16* Qh = (u16*)(ws + 4 * A);
  u16* Ql = (u16*)(ws + 5 * A);
  u16* Kh = (u16*)(ws + 6 * A);
  u16* Kl = (u16*)(ws + 7 * A);
  u16* Vt = (u16*)(ws + 8 * A);
  u16* resb = (u16*)(ws + 9 * A);
  u16* hid = (u16*)(ws);  // aliases slots 0-3 (dead by FFN time)
  float* pe = (float*)(ws + 10 * A);
  u32* m_ws = (u32*)(ws + 10 * A + 1048576);
  char* wbase = ws + 10 * A + 1572864;
  u16* WQth = (u16*)(wbase + 0 * 524288);
  u16* WQtl = (u16*)(wbase + 1 * 524288);
  u16* WKth = (u16*)(wbase + 2 * 524288);
  u16* WKtl = (u16*)(wbase + 3 * 524288);
  u16* WKb = (u16*)(wbase + 4 * 524288);
  u16* WVt_w = (u16*)(wbase + 5 * 524288);
  u16* WKVt = (u16*)(wbase + 6 * 524288);
  u16* f1t = (u16*)(wbase + 7 * 524288);
  u16* f2t = (u16*)(wbase + 7 * 524288 + 2097152);
  char* xbase = wbase + 7 * 524288 + 4194304;
  u16* peh = (u16*)(xbase);
  u16* pel = (u16*)(xbase + 524288);
  u16* zb = (u16*)(xbase + 1048576);
  float* PEK = (float*)(xbase + 1572864);   // [t][n] f32, 1 MB
  float* PEVt = (float*)(xbase + 2621440);  // [v][t] f32, 1 MB

  pe_kernel<<<1024, 256, 0, stream>>>(pe, peh, pel);
  wconv_kernel<<<9216, 256, 0, stream>>>(WQ, WK, WV, f1, f2, WQth, WQtl, WKth, WKtl, WKb, WVt_w,
                                         f1t, f2t, zb);
  prep_kernel<<<32768, 256, 0, stream>>>(queries, pe, q1h, q1l, m_ws);
  // WKVt[v][n] = (WK@WV)^T
  gemm_bt<GM_BF16><<<dim3(4, 4), 256, 0, stream>>>(WVt_w, WKb, 512, 512, 512, WKVt, nullptr,
                                                   nullptr, nullptr);
  // PEK[t][n] = pe @ WK  (split x split -> f32)
  gemm_split<2><<<dim3(4, 4), 256, 0, stream>>>(peh, pel, WKth, WKtl, 512, 512, 512, nullptr,
                                                nullptr, PEK, nullptr);
  // PEVt[v][t] = WKV^T @ pe^T (split B; Al = zeros)
  gemm_split<2><<<dim3(4, 4), 256, 0, stream>>>(WKVt, zb, peh, pel, 512, 512, 512, nullptr,
                                                nullptr, PEVt, nullptr);
  // Q = q1 @ WQ (split); K = q1 @ WK + PEK (split)
  gemm_split<0><<<dim3(128, 4), 256, 0, stream>>>(q1h, q1l, WQth, WQtl, 16384, 512, 512, Qh, Ql,
                                                  nullptr, nullptr);
  gemm_split<1><<<dim3(128, 4), 256, 0, stream>>>(q1h, q1l, WKth, WKtl, 16384, 512, 512, Kh, Kl,
                                                  nullptr, PEK);
  // Vt[v][m] = WKV^T @ q1^T + PEVt
  gemm_bt<GM_BF16PE><<<dim3(4, 128), 256, 0, stream>>>(WKVt, q1h, 512, 16384, 512, Vt, nullptr,
                                                       nullptr, PEVt);
  attn_colmax<<<dim3(256, 8), 256, 0, stream>>>(Qh, Ql, Kh, Kl, m_ws);
  attn_main<<<dim3(256, 8), 256, 0, stream>>>(Qh, Ql, Kh, Kl, Vt, m_ws, qmask, queries, pe, out,
                                              resb);
  gemm_bt<GM_RELU><<<dim3(128, 16), 256, 0, stream>>>(resb, f1t, 16384, 2048, 512, hid, nullptr,
                                                      nullptr, nullptr);
  gemm_bt<GM_ADDF32><<<dim3(128, 4), 256, 0, stream>>>(hid, f2t, 16384, 512, 2048, nullptr, out,
                                                       out, nullptr);
}

// Round 5
// 365.046 us; speedup vs baseline: 1.1430x; 1.1430x over previous
//
#include <hip/hip_runtime.h>
#include <cstdint>
#include <cstddef>

typedef __bf16 bf16x8 __attribute__((ext_vector_type(8)));
typedef float f32x4 __attribute__((ext_vector_type(4)));
using u16 = unsigned short;
using u32 = unsigned int;

// ---------- helpers ----------
__device__ __forceinline__ u16 f2b(float f) {
  u32 u = __float_as_uint(f);
  u32 r = u + 0x7FFFu + ((u >> 16) & 1u);
  return (u16)(r >> 16);
}
__device__ __forceinline__ float b2f(u16 h) { return __uint_as_float((u32)h << 16); }

__device__ __forceinline__ void gload16(const void* g, void* l) {
  __builtin_amdgcn_global_load_lds((const __attribute__((address_space(1))) void*)g,
                                   (__attribute__((address_space(3))) void*)l, 16, 0, 0);
}

__device__ __forceinline__ u32 mapf(float f) {
  u32 u = __float_as_uint(f);
  return (u & 0x80000000u) ? ~u : (u | 0x80000000u);
}
__device__ __forceinline__ float unmapf(u32 k) {
  u32 u = (k & 0x80000000u) ? (k ^ 0x80000000u) : ~k;
  return __uint_as_float(u);
}
__device__ __forceinline__ u32 cvtpk(float lo, float hi) {
  u32 r;
  asm("v_cvt_pk_bf16_f32 %0, %1, %2" : "=v"(r) : "v"(lo), "v"(hi));
  return r;
}

#define MFMA __builtin_amdgcn_mfma_f32_16x16x32_bf16

// ---------- positional encoding ----------
__global__ void pe_kernel(float* __restrict__ pe) {
  int i = blockIdx.x * 256 + threadIdx.x;
  if (i >= 512 * 512) return;
  int t = i >> 9, d = i & 511;
  double ang = (double)t * exp((double)d * (-2.0 / 512.0) * log(10000.0));
  double v = (d & 1) ? cos(ang) : sin(ang);
  pe[i] = (float)(v * 22.627416997969522);
}

// ---------- weight conversion / transposition ----------
__global__ void wconv_kernel(const float* __restrict__ WQ, const float* __restrict__ WK,
                             const float* __restrict__ WV, const float* __restrict__ f1,
                             const float* __restrict__ f2,
                             u16* __restrict__ WQth, u16* __restrict__ WQtl,
                             u16* __restrict__ WKth, u16* __restrict__ WKtl,
                             u16* __restrict__ WKb, u16* __restrict__ WVt,
                             u16* __restrict__ f1t, u16* __restrict__ f2t) {
  int i = blockIdx.x * 256 + threadIdx.x;
  if (i < 262144) {
    int n = i >> 9, k = i & 511;
    float wq = WQ[k * 512 + n];
    u16 h = f2b(wq);
    WQth[i] = h;
    WQtl[i] = f2b(wq - b2f(h));
    float wk = WK[k * 512 + n];
    h = f2b(wk);
    WKth[i] = h;
    WKtl[i] = f2b(wk - b2f(h));
    WKb[i] = f2b(WK[i]);
    WVt[i] = f2b(WV[k * 512 + n]);
  } else if (i < 262144 + 1048576) {
    int i2 = i - 262144;
    int n = i2 >> 9, k = i2 & 511;
    f1t[i2] = f2b(f1[k * 2048 + n]);
  } else if (i < 262144 + 2097152) {
    int i3 = i - 262144 - 1048576;
    int n = i3 >> 11, k = i3 & 2047;
    f2t[i3] = f2b(f2[k * 512 + n]);
  }
}

// ---------- q1/k1 (split bf16) + m_ws zero-init ----------
__global__ void prep_kernel(const float* __restrict__ q, const float* __restrict__ pe,
                            u16* __restrict__ q1h, u16* __restrict__ q1l,
                            u16* __restrict__ k1h, u16* __restrict__ k1l,
                            u32* __restrict__ m0) {
  int i = blockIdx.x * 256 + threadIdx.x;
  if (i < 131072) m0[i] = 0u;  // mapf(-inf) == 0
  if (i >= 32 * 512 * 512) return;
  int td = i & (262144 - 1);
  float p = pe[td];
  float q1 = q[i] + p;
  float k1 = q1 + p;
  u16 h = f2b(q1);
  q1h[i] = h;
  q1l[i] = f2b(q1 - b2f(h));
  h = f2b(k1);
  k1h[i] = h;
  k1l[i] = f2b(k1 - b2f(h));
}

// ---------- generic GEMM: C[M,N] = A[M,K] * B^T ----------
#define GM_BF16 0
#define GM_RELU 2
#define GM_ADDF32 3

template <int MODE>
__global__ __launch_bounds__(256, 3) void gemm_bt(const u16* __restrict__ A,
                                                  const u16* __restrict__ B, int M, int N, int K,
                                                  u16* __restrict__ outb, float* __restrict__ outf,
                                                  const float* __restrict__ res) {
  __shared__ u16 As[128 * 32];
  __shared__ u16 Bs[128 * 32];
  const int tid = threadIdx.x, lane = tid & 63, w = tid >> 6;
  const int wm = w >> 1, wn = w & 1;
  const long aBase = (long)blockIdx.x * 128;
  const long bBase = (long)blockIdx.y * 128;
  f32x4 acc[4][4] = {};
  const int nk = K >> 5;
  for (int kt = 0; kt < nk; ++kt) {
#pragma unroll
    for (int i = 0; i < 2; ++i) {
      const int c = w * 2 + i;
      const int off = c * 1024 + lane * 16;
      const int r = off >> 6, cb = off & 63;
      gload16((const char*)A + ((aBase + r) * (long)K + (long)kt * 32) * 2 + cb,
              (char*)As + c * 1024);
      gload16((const char*)B + ((bBase + r) * (long)K + (long)kt * 32) * 2 + cb,
              (char*)Bs + c * 1024);
    }
    __syncthreads();
    bf16x8 af[4], bfr[4];
#pragma unroll
    for (int x = 0; x < 4; ++x) {
      af[x] = *(const bf16x8*)&As[(wm * 64 + x * 16 + (lane & 15)) * 32 + (lane >> 4) * 8];
      bfr[x] = *(const bf16x8*)&Bs[(wn * 64 + x * 16 + (lane & 15)) * 32 + (lane >> 4) * 8];
    }
#pragma unroll
    for (int mf = 0; mf < 4; ++mf)
#pragma unroll
      for (int nf = 0; nf < 4; ++nf)
        acc[mf][nf] = MFMA(af[mf], bfr[nf], acc[mf][nf], 0, 0, 0);
    __syncthreads();
  }
#pragma unroll
  for (int mf = 0; mf < 4; ++mf)
#pragma unroll
    for (int nf = 0; nf < 4; ++nf) {
      const long row0 = aBase + wm * 64 + mf * 16 + (lane >> 4) * 4;
      const long col = bBase + wn * 64 + nf * 16 + (lane & 15);
#pragma unroll
      for (int j = 0; j < 4; ++j) {
        float v = acc[mf][nf][j];
        const long row = row0 + j;
        if constexpr (MODE == GM_BF16)
          outb[row * N + col] = f2b(v);
        else if constexpr (MODE == GM_RELU)
          outb[row * N + col] = f2b(v > 0.f ? v : 0.f);
        else
          outf[row * N + col] = res[row * N + col] + v;
      }
    }
}

// ---------- split-precision GEMM ----------
__global__ __launch_bounds__(256, 2) void gemm_split(const u16* __restrict__ Ah,
                                                     const u16* __restrict__ Al,
                                                     const u16* __restrict__ Bh,
                                                     const u16* __restrict__ Bl, int M, int N,
                                                     int K, u16* __restrict__ Oh,
                                                     u16* __restrict__ Ol) {
  __shared__ u16 Ash[4096], Asl[4096], Bsh[4096], Bsl[4096];
  const int tid = threadIdx.x, lane = tid & 63, w = tid >> 6;
  const int wm = w >> 1, wn = w & 1;
  const long aBase = (long)blockIdx.x * 128;
  const long bBase = (long)blockIdx.y * 128;
  f32x4 acc[4][4] = {};
  const int nk = K >> 5;
  for (int kt = 0; kt < nk; ++kt) {
#pragma unroll
    for (int i = 0; i < 2; ++i) {
      const int c = w * 2 + i;
      const int off = c * 1024 + lane * 16;
      const int r = off >> 6, cb = off & 63;
      long ga = ((aBase + r) * (long)K + (long)kt * 32) * 2 + cb;
      long gb = ((bBase + r) * (long)K + (long)kt * 32) * 2 + cb;
      gload16((const char*)Ah + ga, (char*)Ash + c * 1024);
      gload16((const char*)Al + ga, (char*)Asl + c * 1024);
      gload16((const char*)Bh + gb, (char*)Bsh + c * 1024);
      gload16((const char*)Bl + gb, (char*)Bsl + c * 1024);
    }
    __syncthreads();
    bf16x8 ah[4], al[4], bh[4], bl[4];
#pragma unroll
    for (int x = 0; x < 4; ++x) {
      int ao = (wm * 64 + x * 16 + (lane & 15)) * 32 + (lane >> 4) * 8;
      int bo = (wn * 64 + x * 16 + (lane & 15)) * 32 + (lane >> 4) * 8;
      ah[x] = *(const bf16x8*)&Ash[ao];
      al[x] = *(const bf16x8*)&Asl[ao];
      bh[x] = *(const bf16x8*)&Bsh[bo];
      bl[x] = *(const bf16x8*)&Bsl[bo];
    }
#pragma unroll
    for (int mf = 0; mf < 4; ++mf)
#pragma unroll
      for (int nf = 0; nf < 4; ++nf) {
        acc[mf][nf] = MFMA(ah[mf], bh[nf], acc[mf][nf], 0, 0, 0);
        acc[mf][nf] = MFMA(ah[mf], bl[nf], acc[mf][nf], 0, 0, 0);
        acc[mf][nf] = MFMA(al[mf], bh[nf], acc[mf][nf], 0, 0, 0);
      }
    __syncthreads();
  }
#pragma unroll
  for (int mf = 0; mf < 4; ++mf)
#pragma unroll
    for (int nf = 0; nf < 4; ++nf) {
      const long row0 = aBase + wm * 64 + mf * 16 + (lane >> 4) * 4;
      const long col = bBase + wn * 64 + nf * 16 + (lane & 15);
#pragma unroll
      for (int j = 0; j < 4; ++j) {
        float v = acc[mf][nf][j];
        const long row = row0 + j;
        u16 h = f2b(v);
        Oh[row * N + col] = h;
        Ol[row * N + col] = f2b(v - b2f(h));
      }
    }
}

// ---------- attention pass 1: column max over q, per (h,b,k) ----------
__global__ __launch_bounds__(256, 4) void attn_colmax(const u16* __restrict__ Qh,
                                                      const u16* __restrict__ Ql,
                                                      const u16* __restrict__ Kh,
                                                      const u16* __restrict__ Kl,
                                                      u32* __restrict__ mg) {
  __shared__ u16 Qsh[4096], Qsl[4096];  // [64 rows][64 u16], XOR-swizzled
  __shared__ u16 Ksh[4096], Ksl[4096];
  __shared__ u32 mloc[512];
  const int tid = threadIdx.x, lane = tid & 63, w = tid >> 6;
  const int ql = lane & 15, g = lane >> 4;
  const int hb = blockIdx.x, b = hb >> 3, h = hb & 7, qc = blockIdx.y;
  mloc[tid] = 0u;
  mloc[tid + 256] = 0u;
  const int srccb = 16 * ((lane & 7) ^ ((lane >> 3) & 7));
#pragma unroll
  for (int i = 0; i < 2; ++i) {
    const int c = w * 2 + i;
    const int r = c * 8 + (lane >> 3);
    long gb = ((long)(b * 512 + qc * 64 + r) * 512 + h * 64) * 2 + srccb;
    gload16((const char*)Qh + gb, (char*)Qsh + c * 1024);
    gload16((const char*)Ql + gb, (char*)Qsl + c * 1024);
  }
  __syncthreads();
  const int qrow = w * 16 + ql;
  const int sw0 = ((g * 16) ^ ((ql & 7) * 16)) >> 1;
  const int sw1 = ((64 + g * 16) ^ ((ql & 7) * 16)) >> 1;
  bf16x8 qh0 = *(const bf16x8*)&Qsh[qrow * 64 + sw0];
  bf16x8 ql0 = *(const bf16x8*)&Qsl[qrow * 64 + sw0];
  bf16x8 qh1 = *(const bf16x8*)&Qsh[qrow * 64 + sw1];
  bf16x8 ql1 = *(const bf16x8*)&Qsl[qrow * 64 + sw1];
  for (int kc = 0; kc < 8; ++kc) {
#pragma unroll
    for (int i = 0; i < 2; ++i) {
      const int c = w * 2 + i;
      const int r = c * 8 + (lane >> 3);
      long gb = ((long)(b * 512 + kc * 64 + r) * 512 + h * 64) * 2 + srccb;
      gload16((const char*)Kh + gb, (char*)Ksh + c * 1024);
      gload16((const char*)Kl + gb, (char*)Ksl + c * 1024);
    }
    __syncthreads();
#pragma unroll
    for (int kt = 0; kt < 4; ++kt) {
      const int krow = kt * 16 + ql;
      bf16x8 kh0 = *(const bf16x8*)&Ksh[krow * 64 + sw0];
      bf16x8 kl0 = *(const bf16x8*)&Ksl[krow * 64 + sw0];
      bf16x8 kh1 = *(const bf16x8*)&Ksh[krow * 64 + sw1];
      bf16x8 kl1 = *(const bf16x8*)&Ksl[krow * 64 + sw1];
      f32x4 acc = {0.f, 0.f, 0.f, 0.f};
      acc = MFMA(qh0, kh0, acc, 0, 0, 0);
      acc = MFMA(qh0, kl0, acc, 0, 0, 0);
      acc = MFMA(ql0, kh0, acc, 0, 0, 0);
      acc = MFMA(qh1, kh1, acc, 0, 0, 0);
      acc = MFMA(qh1, kl1, acc, 0, 0, 0);
      acc = MFMA(ql1, kh1, acc, 0, 0, 0);
      float v = fmaxf(fmaxf(acc[0], acc[1]), fmaxf(acc[2], acc[3]));
      v = fmaxf(v, __shfl_xor(v, 16));
      v = fmaxf(v, __shfl_xor(v, 32));
      if (lane < 16) atomicMax(&mloc[kc * 64 + kt * 16 + ql], mapf(v));
    }
    __syncthreads();
  }
  for (int k = tid; k < 512; k += 256) atomicMax(&mg[(long)hb * 512 + k], mloc[k]);
}

// ---------- attention pass 2: ONLINE S^T -> softmax -> PV, no big S buffer ----------
__global__ __launch_bounds__(256, 3) void attn_main(
    const u16* __restrict__ Qh, const u16* __restrict__ Ql, const u16* __restrict__ Kh,
    const u16* __restrict__ Kl, const u16* __restrict__ Vt, const u32* __restrict__ mg,
    const int* __restrict__ qmask, const u16* __restrict__ q1h, const u16* __restrict__ q1l,
    float* __restrict__ resf, u16* __restrict__ resb) {
  __shared__ u16 Qsh[4096], Qsl[4096];  // [64][64] u16, XOR-swizzled
  __shared__ u16 Ksh[4096], Ksl[4096];
  __shared__ float mks[512];
  const int tid = threadIdx.x, lane = tid & 63, w = tid >> 6;
  const int qll = lane & 15, g = lane >> 4;
  const int hb = blockIdx.x, b = hb >> 3, h = hb & 7, qc = blockIdx.y;
  const int qm = qmask[b];
  for (int k = tid; k < 512; k += 256) mks[k] = 0.125f * unmapf(mg[(long)hb * 512 + k]);
  const int srccb = 16 * ((lane & 7) ^ ((lane >> 3) & 7));
#pragma unroll
  for (int i = 0; i < 2; ++i) {
    const int c = w * 2 + i;
    const int r = c * 8 + (lane >> 3);
    long gb = ((long)(b * 512 + qc * 64 + r) * 512 + h * 64) * 2 + srccb;
    gload16((const char*)Qh + gb, (char*)Qsh + c * 1024);
    gload16((const char*)Ql + gb, (char*)Qsl + c * 1024);
  }
  __syncthreads();
  const int qrow = w * 16 + qll;
  const int sw0 = ((g * 16) ^ ((qll & 7) * 16)) >> 1;
  const int sw1 = ((64 + g * 16) ^ ((qll & 7) * 16)) >> 1;
  bf16x8 qh0 = *(const bf16x8*)&Qsh[qrow * 64 + sw0];
  bf16x8 qh1 = *(const bf16x8*)&Qsh[qrow * 64 + sw1];
  bf16x8 qlo0 = *(const bf16x8*)&Qsl[qrow * 64 + sw0];
  bf16x8 qlo1 = *(const bf16x8*)&Qsl[qrow * 64 + sw1];
  // online state
  f32x4 o[4] = {};
  float mr = -3.0e38f, rsum = 0.f;
  const u16* vb = Vt + (long)(h * 64) * 16384 + b * 512;
  const int src0 = (g & 1) * 32 + qll;
  const int src1 = src0 + 16;
  const bool lowh = g < 2;
  for (int kc = 0; kc < 8; ++kc) {
    // prefetch this chunk's V fragments (overlaps with K staging + S MFMAs)
    bf16x8 vf[2][4];
#pragma unroll
    for (int k2 = 0; k2 < 2; ++k2)
#pragma unroll
      for (int nf = 0; nf < 4; ++nf)
        vf[k2][nf] =
            *(const bf16x8*)&vb[(long)(nf * 16 + qll) * 16384 + (kc * 2 + k2) * 32 + g * 8];
    // stage K chunk
#pragma unroll
    for (int i = 0; i < 2; ++i) {
      const int c = w * 2 + i;
      const int r = c * 8 + (lane >> 3);
      long gb = ((long)(b * 512 + kc * 64 + r) * 512 + h * 64) * 2 + srccb;
      gload16((const char*)Kh + gb, (char*)Ksh + c * 1024);
      gload16((const char*)Kl + gb, (char*)Ksl + c * 1024);
    }
    __syncthreads();
    // S^T tile: s4[kt][j] = S^T[k = kc*64 + kt*16 + g*4 + j][q]
    f32x4 s4[4] = {};
#pragma unroll
    for (int kt = 0; kt < 4; ++kt) {
      const int krow = kt * 16 + qll;
      bf16x8 kh0 = *(const bf16x8*)&Ksh[krow * 64 + sw0];
      bf16x8 kl0 = *(const bf16x8*)&Ksl[krow * 64 + sw0];
      bf16x8 kh1 = *(const bf16x8*)&Ksh[krow * 64 + sw1];
      bf16x8 kl1 = *(const bf16x8*)&Ksl[krow * 64 + sw1];
      s4[kt] = MFMA(kh0, qh0, s4[kt], 0, 0, 0);
      s4[kt] = MFMA(kh0, qlo0, s4[kt], 0, 0, 0);
      s4[kt] = MFMA(kl0, qh0, s4[kt], 0, 0, 0);
      s4[kt] = MFMA(kh1, qh1, s4[kt], 0, 0, 0);
      s4[kt] = MFMA(kh1, qlo1, s4[kt], 0, 0, 0);
      s4[kt] = MFMA(kl1, qh1, s4[kt], 0, 0, 0);
    }
    __syncthreads();
    // z = s/8 - m[k]; running rowmax + rescale
    float pm = mr;
#pragma unroll
    for (int kt = 0; kt < 4; ++kt) {
      f32x4 mrow = *(const f32x4*)&mks[kc * 64 + kt * 16 + g * 4];
#pragma unroll
      for (int j = 0; j < 4; ++j) {
        float z = s4[kt][j] * 0.125f - mrow[j];
        s4[kt][j] = z;
        pm = fmaxf(pm, z);
      }
    }
    pm = fmaxf(pm, __shfl_xor(pm, 16));
    pm = fmaxf(pm, __shfl_xor(pm, 32));
    const float f = __expf(mr - pm);  // <= 1; first chunk: exp(-inf) = 0
    mr = pm;
    rsum *= f;
#pragma unroll
    for (int nf = 0; nf < 4; ++nf) {
      o[nf][0] *= f;
      o[nf][1] *= f;
      o[nf][2] *= f;
      o[nf][3] *= f;
    }
    // exp + pack (unnormalized; normalize at end)
    u32 pk0[4], pk1[4];
#pragma unroll
    for (int kt = 0; kt < 4; ++kt) {
      float p0 = __expf(s4[kt][0] - mr);
      float p1 = __expf(s4[kt][1] - mr);
      float p2 = __expf(s4[kt][2] - mr);
      float p3 = __expf(s4[kt][3] - mr);
      rsum += (p0 + p1) + (p2 + p3);
      pk0[kt] = cvtpk(p0, p1);
      pk1[kt] = cvtpk(p2, p3);
    }
    // PV for this chunk (2 k-slices of 32)
#pragma unroll
    for (int k2 = 0; k2 < 2; ++k2) {
      const int fA = 2 * k2, fB = 2 * k2 + 1;
      u32 a00 = __shfl(pk0[fA], src0), b00 = __shfl(pk0[fB], src0);
      u32 a10 = __shfl(pk1[fA], src0), b10 = __shfl(pk1[fB], src0);
      u32 a01 = __shfl(pk0[fA], src1), b01 = __shfl(pk0[fB], src1);
      u32 a11 = __shfl(pk1[fA], src1), b11 = __shfl(pk1[fB], src1);
      union {
        u32 u[4];
        bf16x8 v;
      } pf;
      pf.u[0] = lowh ? a00 : b00;
      pf.u[1] = lowh ? a10 : b10;
      pf.u[2] = lowh ? a01 : b01;
      pf.u[3] = lowh ? a11 : b11;
#pragma unroll
      for (int nf = 0; nf < 4; ++nf) o[nf] = MFMA(vf[k2][nf], pf.v, o[nf], 0, 0, 0);
    }
  }
  // finalize: cross-lane sum, mask, normalize
  rsum += __shfl_xor(rsum, 16);
  rsum += __shfl_xor(rsum, 32);
  const int qg = qc * 64 + w * 16 + qll;
  const float sc = (qg < qm) ? (1.0f / rsum) : 0.0f;
  // epilogue: O[q][d]*sc + q1 -> resf (f32) and resb (bf16)
#pragma unroll
  for (int nf = 0; nf < 4; ++nf) {
    const int col = h * 64 + nf * 16 + g * 4;
    const long idx = (long)(b * 512 + qg) * 512 + col;
    ushort4 qh4 = *(const ushort4*)&q1h[idx];
    ushort4 ql4 = *(const ushort4*)&q1l[idx];
    float v0 = o[nf][0] * sc + b2f(qh4.x) + b2f(ql4.x);
    float v1 = o[nf][1] * sc + b2f(qh4.y) + b2f(ql4.y);
    float v2 = o[nf][2] * sc + b2f(qh4.z) + b2f(ql4.z);
    float v3 = o[nf][3] * sc + b2f(qh4.w) + b2f(ql4.w);
    *(float4*)&resf[idx] = make_float4(v0, v1, v2, v3);
    ushort4 rb = {f2b(v0), f2b(v1), f2b(v2), f2b(v3)};
    *(ushort4*)&resb[idx] = rb;
  }
}

// ---------- launch ----------
extern "C" void kernel_launch(void* const* d_in, const int* in_sizes, int n_in, void* d_out,
                              int out_size, void* d_ws, size_t ws_size, hipStream_t stream) {
  (void)in_sizes;
  (void)n_in;
  (void)out_size;
  (void)ws_size;
  const float* queries = (const float*)d_in[0];
  const int* qmask = (const int*)d_in[2];
  const float* WQ = (const float*)d_in[4];
  const float* WK = (const float*)d_in[5];
  const float* WV = (const float*)d_in[6];
  const float* f1 = (const float*)d_in[7];
  const float* f2 = (const float*)d_in[8];
  float* out = (float*)d_out;
  char* ws = (char*)d_ws;
  const size_t A = 16777216;
  u16* q1h = (u16*)(ws + 0 * A);
  u16* q1l = (u16*)(ws + 1 * A);
  u16* k1h = (u16*)(ws + 2 * A);
  u16* k1l = (u16*)(ws + 3 * A);
  u16* Qh = (u16*)(ws + 4 * A);
  u16* Ql = (u16*)(ws + 5 * A);
  u16* Kh = (u16*)(ws + 6 * A);
  u16* Kl = (u16*)(ws + 7 * A);
  u16* Vt = (u16*)(ws + 8 * A);
  u16* resb = (u16*)(ws + 9 * A);
  u16* hid = (u16*)(ws + 2 * A);  // aliases k1h..Ql region? no: aliases slots 2,3 only (32MB) -- need 64MB
  // hid needs 64 MiB: alias slots 0-3 (q1h,q1l,k1h,k1l). q1h/q1l are read by attn_main,
  // which completes before FFN1 launches (stream-ordered), so the alias is safe.
  hid = (u16*)(ws + 0 * A);
  float* pe = (float*)(ws + 10 * A);
  u32* m_ws = (u32*)(ws + 10 * A + 1048576);
  char* wbase = ws + 10 * A + 1572864;
  u16* WQth = (u16*)(wbase + 0 * 524288);
  u16* WQtl = (u16*)(wbase + 1 * 524288);
  u16* WKth = (u16*)(wbase + 2 * 524288);
  u16* WKtl = (u16*)(wbase + 3 * 524288);
  u16* WKb = (u16*)(wbase + 4 * 524288);
  u16* WVt_w = (u16*)(wbase + 5 * 524288);
  u16* WKVt = (u16*)(wbase + 6 * 524288);
  u16* f1t = (u16*)(wbase + 7 * 524288);
  u16* f2t = (u16*)(wbase + 7 * 524288 + 2097152);

  pe_kernel<<<1024, 256, 0, stream>>>(pe);
  wconv_kernel<<<9216, 256, 0, stream>>>(WQ, WK, WV, f1, f2, WQth, WQtl, WKth, WKtl, WKb, WVt_w,
                                         f1t, f2t);
  prep_kernel<<<32768, 256, 0, stream>>>(queries, pe, q1h, q1l, k1h, k1l, m_ws);
  // WKVt[v][n] = (WK@WV)^T : C = WVt_w * WKb^T
  gemm_bt<GM_BF16><<<dim3(4, 4), 256, 0, stream>>>(WVt_w, WKb, 512, 512, 512, WKVt, nullptr,
                                                   nullptr);
  gemm_split<<<dim3(128, 4), 256, 0, stream>>>(q1h, q1l, WQth, WQtl, 16384, 512, 512, Qh, Ql);
  gemm_split<<<dim3(128, 4), 256, 0, stream>>>(k1h, k1l, WKth, WKtl, 16384, 512, 512, Kh, Kl);
  // Vt[v][m] = V^T directly: C = WKVt * k1h^T
  gemm_bt<GM_BF16><<<dim3(4, 128), 256, 0, stream>>>(WKVt, k1h, 512, 16384, 512, Vt, nullptr,
                                                     nullptr);
  attn_colmax<<<dim3(256, 8), 256, 0, stream>>>(Qh, Ql, Kh, Kl, m_ws);
  attn_main<<<dim3(256, 8), 256, 0, stream>>>(Qh, Ql, Kh, Kl, Vt, m_ws, qmask, q1h, q1l, out,
                                              resb);
  gemm_bt<GM_RELU><<<dim3(128, 16), 256, 0, stream>>>(resb, f1t, 16384, 2048, 512, hid, nullptr,
                                                      nullptr);
  gemm_bt<GM_ADDF32><<<dim3(128, 4), 256, 0, stream>>>(hid, f2t, 16384, 512, 2048, nullptr, out,
                                                       out);
}